// Round 6
// baseline (393.283 us; speedup 1.0000x reference)
//
#include <hip/hip_runtime.h>

// ModelQuantLinear: int8-act × int4-weight per-tensor quantized linear, 8192×4096 @ 4096×4096^T.
// Exact integer GEMM via mfma_i32_16x16x64_i8, 256x256 tile, BK=128B, whole-tile double buffer,
// 4 phases/tile with per-phase barriers (round-4 skeleton) + software-pipelined fragment reads:
// each phase issues NEXT phase's ds_reads, then MFMAs current phase (LDS pipe hides under MFMA).

typedef int v4i __attribute__((ext_vector_type(4)));

#define AS1(p) ((const __attribute__((address_space(1))) void*)(p))
#define AS3(p) ((__attribute__((address_space(3))) void*)(p))

#define GM 8192
#define GN 4096
#define GK 4096
#define NBN 16   // 4096/256 col tiles
#define NWG 512  // (8192/256)*(4096/256)

// ---------------- max|x| (float4 grid-stride, wave+block reduce, 1 atomic/block) ------------
__global__ __launch_bounds__(256) void maxabs_kernel(const float* __restrict__ x, int n4,
                                                     unsigned* __restrict__ slot) {
  __shared__ float red[4];
  int tid = blockIdx.x * blockDim.x + threadIdx.x;
  int stride = gridDim.x * blockDim.x;
  float m = 0.0f;
  const float4* x4 = (const float4*)x;
  for (int i = tid; i < n4; i += stride) {
    float4 v = x4[i];
    m = fmaxf(m, fmaxf(fmaxf(fabsf(v.x), fabsf(v.y)), fmaxf(fabsf(v.z), fabsf(v.w))));
  }
  for (int off = 32; off; off >>= 1) m = fmaxf(m, __shfl_xor(m, off));
  if ((threadIdx.x & 63) == 0) red[threadIdx.x >> 6] = m;
  __syncthreads();
  if (threadIdx.x == 0) {
    float b = fmaxf(fmaxf(red[0], red[1]), fmaxf(red[2], red[3]));
    atomicMax(slot, __float_as_uint(b));
  }
}

// ---------------- per-tensor quantize to int8 storage (reciprocal-mul) ----------------------
__global__ __launch_bounds__(256) void quant_kernel(const float* __restrict__ x,
                                                    signed char* __restrict__ q, int n4,
                                                    const unsigned* __restrict__ slot,
                                                    float qmaxv, float qlo, float qhi) {
  float s = fmaxf(__uint_as_float(*slot) / qmaxv, 1e-8f);
  float inv = 1.0f / s;
  int tid = blockIdx.x * blockDim.x + threadIdx.x;
  int stride = gridDim.x * blockDim.x;
  const float4* x4 = (const float4*)x;
  int* q4 = (int*)q;
  for (int i = tid; i < n4; i += stride) {
    float4 v = x4[i];
    int a0 = (int)fminf(fmaxf(rintf(v.x * inv), qlo), qhi);
    int a1 = (int)fminf(fmaxf(rintf(v.y * inv), qlo), qhi);
    int a2 = (int)fminf(fmaxf(rintf(v.z * inv), qlo), qhi);
    int a3 = (int)fminf(fmaxf(rintf(v.w * inv), qlo), qhi);
    q4[i] = (a0 & 255) | ((a1 & 255) << 8) | ((a2 & 255) << 16) | ((a3 & 255) << 24);
  }
}

// ---------------- i8 GEMM, 256x256 tile, BK=128 B, 8 waves (2Mx4N) ---------------------------
// Per tile t (read buffer db=t&1; stages during tile t fill ndb for t+1):
//   gate: issue STAGE B0(t+1); vmcnt(2) [t=31: vmcnt(0)]; s_barrier -> tile t fully in LDS.
//     (outstanding at wait: B0..A1(t)=8 + B0(t+1)=2 -> drain to 2 leaves exactly t+1's B0.)
//   pre-read: af_a<-A(h0,k0), bf_a<-B(k0)            (8 ds_read_b128)
//   Ph0: read af_b<-A(h1,k0) (4);          STAGE B1(t+1); MFMA16(0, af_a, bf_a); barrier
//   Ph1: read af_a<-A(h0,k1), bf_b<-B(k1) (8); STAGE A0(t+1); MFMA16(4, af_b, bf_a); barrier
//   Ph2: read af_b<-A(h1,k1) (4);          STAGE A1(t+1); MFMA16(0, af_a, bf_b); barrier
//   Ph3:                                                  MFMA16(4, af_b, bf_b)   [gate next]
// No explicit lgkmcnt: compiler emits counted waits from register deps, so each phase's MFMAs
// wait only on the PREVIOUS phase's (already-landed) reads while this phase's reads fly.
// WAR on LDS: stage(ndb) at tile t overwrites data last read at t-1; those reads were consumed
// by t-1's MFMAs (HW interlock) before the gate barrier. Reads of tile t only after its gate.
// Swizzle: 16B granule g_phys = g_log ^ (row&7), inverse-applied on global source (rule 21).
__global__ __launch_bounds__(512, 2) void gemm_i8_kernel(const signed char* __restrict__ Xq,
                                                         const signed char* __restrict__ Wq,
                                                         const float* __restrict__ bias,
                                                         const unsigned* __restrict__ slots,
                                                         float* __restrict__ Y,
                                                         unsigned* __restrict__ maxY) {
  __shared__ signed char smem[131072];
  const int tid = threadIdx.x;
  const int wid = tid >> 6, lane = tid & 63;
  const int wr = wid >> 2, wc = wid & 3;
  const int lr = lane & 15, lg = lane >> 4;

  // XCD-aware bijective swizzle (512 % 8 == 0)
  const int bid = (int)blockIdx.x;
  const int swz = (bid & 7) * (NWG / 8) + (bid >> 3);
  const int brow = (swz / NBN) * 256;
  const int bcol = (swz % NBN) * 256;

  // staging thread map: row-in-half, inverse-swizzled source granule
  const int srr = tid >> 3;
  const int sgl = (tid & 7) ^ (srr & 7);

  // per-frag LDS row offsets / swizzle keys (invariant over tiles & kslices)
  int aoff[4], asw[4], boff[4], bsw[4];
#pragma unroll
  for (int mm = 0; mm < 4; ++mm) {
    int hr = wr * 64 + mm * 16 + lr;
    aoff[mm] = hr * 128;
    asw[mm] = hr & 7;
  }
#pragma unroll
  for (int nn = 0; nn < 4; ++nn) {
    int hr = wc * 32 + (nn & 1) * 16 + lr;
    boff[nn] = hr * 128;
    bsw[nn] = hr & 7;
  }

#define ASLOT(db, h) (smem + ((db) * 2 + (h)) * 16384)
#define BSLOT(db, h) (smem + 65536 + ((db) * 2 + (h)) * 16384)
// one half-tile (128 rows x 128 B) = 2 x global_load_lds(16B) per wave
#define STAGE(gptr, grow0, kofs, slot)                                                        \
  {                                                                                           \
    const signed char* _s0 = (gptr) + (size_t)((grow0) + srr) * GK + (kofs) + sgl * 16;       \
    __builtin_amdgcn_global_load_lds(AS1(_s0), AS3((slot) + wid * 1024), 16, 0, 0);           \
    __builtin_amdgcn_global_load_lds(AS1(_s0 + (size_t)64 * GK),                              \
                                     AS3((slot) + 8192 + wid * 1024), 16, 0, 0);              \
  }
#define LDA(mm, db, h, kk) \
  *(const v4i*)(ASLOT(db, h) + aoff[mm] + ((((kk)*4 + lg) ^ asw[mm]) << 4))
#define LDB(nn, db, kk) \
  *(const v4i*)(BSLOT(db, (nn) >> 1) + boff[nn] + ((((kk)*4 + lg) ^ bsw[nn]) << 4))
#define MFMA16(arow, AF, BF)                                                                  \
  __builtin_amdgcn_s_setprio(1);                                                              \
  _Pragma("unroll") for (int mm = 0; mm < 4; ++mm)                                            \
      _Pragma("unroll") for (int nn = 0; nn < 4; ++nn)                                        \
          acc[(arow) + mm][nn] =                                                              \
      __builtin_amdgcn_mfma_i32_16x16x64_i8(AF[mm], BF[nn], acc[(arow) + mm][nn], 0, 0, 0);   \
  __builtin_amdgcn_s_setprio(0);
#define BAR()                         \
  __builtin_amdgcn_s_barrier();       \
  asm volatile("" ::: "memory");

  // prologue: tile 0's four halves (steady-state issue order)
  STAGE(Wq, bcol, 0, BSLOT(0, 0));
  STAGE(Wq, bcol + 128, 0, BSLOT(0, 1));
  STAGE(Xq, brow, 0, ASLOT(0, 0));
  STAGE(Xq, brow + 128, 0, ASLOT(0, 1));

  v4i acc[8][4] = {};

#pragma unroll 2
  for (int t = 0; t < 32; ++t) {
    const int db = t & 1, ndb = db ^ 1;
    const int kof = (t + 1) * 128;
    v4i af_a[4], af_b[4], bf_a[4], bf_b[4];

    // ---- gate: issue next B0, drain this tile's four halves, sync
    if (t < 31) STAGE(Wq, bcol, kof, BSLOT(ndb, 0));
    if (t == 31)
      asm volatile("s_waitcnt vmcnt(0)" ::: "memory");
    else
      asm volatile("s_waitcnt vmcnt(2)" ::: "memory");
    BAR()

    // ---- pre-read for Ph0
#pragma unroll
    for (int mm = 0; mm < 4; ++mm) af_a[mm] = LDA(mm, db, 0, 0);
#pragma unroll
    for (int nn = 0; nn < 4; ++nn) bf_a[nn] = LDB(nn, db, 0);

    // ---- Ph0: read next (af_b@k0,h1); stage B1(t+1); MFMA (af_a,bf_a)
#pragma unroll
    for (int mm = 0; mm < 4; ++mm) af_b[mm] = LDA(mm, db, 1, 0);
    if (t < 31) STAGE(Wq, bcol + 128, kof, BSLOT(ndb, 1));
    MFMA16(0, af_a, bf_a)
    BAR()

    // ---- Ph1: read next (af_a@k1,h0 + bf_b@k1); stage A0(t+1); MFMA (af_b,bf_a)
#pragma unroll
    for (int mm = 0; mm < 4; ++mm) af_a[mm] = LDA(mm, db, 0, 1);
#pragma unroll
    for (int nn = 0; nn < 4; ++nn) bf_b[nn] = LDB(nn, db, 1);
    if (t < 31) STAGE(Xq, brow, kof, ASLOT(ndb, 0));
    MFMA16(4, af_b, bf_a)
    BAR()

    // ---- Ph2: read next (af_b@k1,h1); stage A1(t+1); MFMA (af_a,bf_b)
#pragma unroll
    for (int mm = 0; mm < 4; ++mm) af_b[mm] = LDA(mm, db, 1, 1);
    if (t < 31) STAGE(Xq, brow + 128, kof, ASLOT(ndb, 1));
    MFMA16(0, af_a, bf_b)
    BAR()

    // ---- Ph3: pure MFMA (af_b,bf_b); gate barrier follows
    MFMA16(4, af_b, bf_b)
  }

  // Epilogue: y = acc*(s_in*s_w) + round(b/s_b)*s_b ; track max|y| (block-reduced atomic)
  float s_in = fmaxf(__uint_as_float(slots[0]) / 127.0f, 1e-8f);
  float s_w = fmaxf(__uint_as_float(slots[1]) / 7.0f, 1e-8f);
  float s_b = s_in * s_w;
  float lmax = 0.0f;
#pragma unroll
  for (int n = 0; n < 4; ++n) {
    int o = bcol + (n >> 1) * 128 + wc * 32 + (n & 1) * 16 + lr;
    float bdq = rintf(bias[o] / s_b) * s_b;
#pragma unroll
    for (int m = 0; m < 8; ++m) {
      int t0 = brow + (m >> 2) * 128 + wr * 64 + (m & 3) * 16 + (lg << 2);
#pragma unroll
      for (int r2 = 0; r2 < 4; ++r2) {
        float yv = (float)acc[m][n][r2] * s_b + bdq;
        Y[(size_t)(t0 + r2) * GN + o] = yv;
        lmax = fmaxf(lmax, fabsf(yv));
      }
    }
  }
  for (int off = 32; off; off >>= 1) lmax = fmaxf(lmax, __shfl_xor(lmax, off));
  // fred sits in smem[0..32) = ASLOT(0,0); tile 31 read db=1 buffers only -> no collision.
  float* fred = (float*)smem;
  if (lane == 0) fred[wid] = lmax;
  __syncthreads();
  if (tid == 0) {
    float m = fred[0];
#pragma unroll
    for (int i = 1; i < 8; ++i) m = fmaxf(m, fred[i]);
    atomicMax(maxY, __float_as_uint(m));
  }
#undef STAGE
#undef ASLOT
#undef BSLOT
#undef LDA
#undef LDB
#undef MFMA16
#undef BAR
}

// ---------------- output quant in-place on d_out --------------------------------------------
__global__ __launch_bounds__(256) void quant_out_kernel(float* __restrict__ y, int n4,
                                                        const unsigned* __restrict__ slot) {
  float s = fmaxf(__uint_as_float(*slot) / 127.0f, 1e-8f);
  float inv = 1.0f / s;
  int tid = blockIdx.x * blockDim.x + threadIdx.x;
  int stride = gridDim.x * blockDim.x;
  float4* y4 = (float4*)y;
  for (int i = tid; i < n4; i += stride) {
    float4 v = y4[i];
    v.x = fminf(fmaxf(rintf(v.x * inv), -128.0f), 127.0f) * s;
    v.y = fminf(fmaxf(rintf(v.y * inv), -128.0f), 127.0f) * s;
    v.z = fminf(fmaxf(rintf(v.z * inv), -128.0f), 127.0f) * s;
    v.w = fminf(fmaxf(rintf(v.w * inv), -128.0f), 127.0f) * s;
    y4[i] = v;
  }
}

extern "C" void kernel_launch(void* const* d_in, const int* in_sizes, int n_in,
                              void* d_out, int out_size, void* d_ws, size_t ws_size,
                              hipStream_t stream) {
  const float* inp = (const float*)d_in[0];  // [8192,4096]
  const float* W = (const float*)d_in[1];    // [4096,4096]
  const float* b = (const float*)d_in[2];    // [4096]
  float* out = (float*)d_out;                // [8192,4096]

  unsigned* slots = (unsigned*)d_ws;  // [0]=max|X|, [1]=max|W|, [2]=max|Y| (float bits)
  signed char* Xq = (signed char*)d_ws + 256;
  signed char* Wq = Xq + (size_t)GM * GK;

  const int nX = GM * GK;
  const int nW = GN * GK;

  // zero the atomic-max slots (ws is NOT re-poisoned between timed replays)
  hipMemsetAsync(d_ws, 0, 16, stream);

  maxabs_kernel<<<1024, 256, 0, stream>>>(inp, nX / 4, slots + 0);
  maxabs_kernel<<<512, 256, 0, stream>>>(W, nW / 4, slots + 1);

  quant_kernel<<<1024, 256, 0, stream>>>(inp, Xq, nX / 4, slots + 0, 127.0f, -128.0f, 127.0f);
  quant_kernel<<<512, 256, 0, stream>>>(W, Wq, nW / 4, slots + 1, 7.0f, -8.0f, 7.0f);

  gemm_i8_kernel<<<NWG, 512, 0, stream>>>(Xq, Wq, b, slots, out, slots + 2);

  quant_out_kernel<<<1024, 256, 0, stream>>>(out, (GM * GN) / 4, slots + 2);
}

// Round 7
// 303.340 us; speedup vs baseline: 1.2965x; 1.2965x over previous
//
#include <hip/hip_runtime.h>

// ModelQuantLinear: int8-act × int4-weight per-tensor quantized linear, 8192×4096 @ 4096×4096^T.
// Exact integer GEMM via mfma_i32_16x16x64_i8. 128x128 tile, BK=128B, 4 waves (2x2),
// 64 KiB LDS double-buffer -> 2 blocks/CU so cross-block wave overlap hides per-phase stalls
// (round-4 phase skeleton kept verbatim; only geometry/occupancy changed).

typedef int v4i __attribute__((ext_vector_type(4)));

#define AS1(p) ((const __attribute__((address_space(1))) void*)(p))
#define AS3(p) ((__attribute__((address_space(3))) void*)(p))

#define GM 8192
#define GN 4096
#define GK 4096
#define NWG 2048  // (8192/128)*(4096/128)

// ---------------- max|x| (float4 grid-stride, wave+block reduce, 1 atomic/block) ------------
__global__ __launch_bounds__(256) void maxabs_kernel(const float* __restrict__ x, int n4,
                                                     unsigned* __restrict__ slot) {
  __shared__ float red[4];
  int tid = blockIdx.x * blockDim.x + threadIdx.x;
  int stride = gridDim.x * blockDim.x;
  float m = 0.0f;
  const float4* x4 = (const float4*)x;
  for (int i = tid; i < n4; i += stride) {
    float4 v = x4[i];
    m = fmaxf(m, fmaxf(fmaxf(fabsf(v.x), fabsf(v.y)), fmaxf(fabsf(v.z), fabsf(v.w))));
  }
  for (int off = 32; off; off >>= 1) m = fmaxf(m, __shfl_xor(m, off));
  if ((threadIdx.x & 63) == 0) red[threadIdx.x >> 6] = m;
  __syncthreads();
  if (threadIdx.x == 0) {
    float b = fmaxf(fmaxf(red[0], red[1]), fmaxf(red[2], red[3]));
    atomicMax(slot, __float_as_uint(b));
  }
}

// ---------------- per-tensor quantize to int8 storage (reciprocal-mul) ----------------------
__global__ __launch_bounds__(256) void quant_kernel(const float* __restrict__ x,
                                                    signed char* __restrict__ q, int n4,
                                                    const unsigned* __restrict__ slot,
                                                    float qmaxv, float qlo, float qhi) {
  float s = fmaxf(__uint_as_float(*slot) / qmaxv, 1e-8f);
  float inv = 1.0f / s;
  int tid = blockIdx.x * blockDim.x + threadIdx.x;
  int stride = gridDim.x * blockDim.x;
  const float4* x4 = (const float4*)x;
  int* q4 = (int*)q;
  for (int i = tid; i < n4; i += stride) {
    float4 v = x4[i];
    int a0 = (int)fminf(fmaxf(rintf(v.x * inv), qlo), qhi);
    int a1 = (int)fminf(fmaxf(rintf(v.y * inv), qlo), qhi);
    int a2 = (int)fminf(fmaxf(rintf(v.z * inv), qlo), qhi);
    int a3 = (int)fminf(fmaxf(rintf(v.w * inv), qlo), qhi);
    q4[i] = (a0 & 255) | ((a1 & 255) << 8) | ((a2 & 255) << 16) | ((a3 & 255) << 24);
  }
}

// ---------------- i8 GEMM, 128x128 tile, BK=128 B, 4 waves (2Mx2N), 2 blocks/CU -------------
// Per tile t (read buffer db=t&1; stages during tile t fill ndb for t+1):
//   gate: vmcnt(0) [tile t's 8 staging loads, issued during t-1, have landed]; s_barrier.
//   P0: read af@k0 (4) + bf@k0 (4); STAGE A(t+1)->ndb; lgkmcnt(0); 16 MFMA (k0); barrier
//   P1: read af@k1 (4) + bf@k1 (4); STAGE B(t+1)->ndb; lgkmcnt(0); 16 MFMA (k1); barrier
// WAR: stage(ndb) in tile t overwrites data last read in t-1, whose reads completed before
// t-1's P1 barrier (lgkmcnt(0) precedes MFMA precedes barrier). Reads of t after its gate.
// Cross-block overlap: 64 KiB LDS + <=256 VGPR -> 2 blocks/CU; SIMD's 2 waves come from
// different blocks, so one block's gate/lgkm stalls hide under the other's MFMA clusters.
// Swizzle: 16B granule g_phys = g_log ^ (row&7), inverse-applied on global source (rule 21).
__global__ __launch_bounds__(256, 2) void gemm_i8_kernel(const signed char* __restrict__ Xq,
                                                         const signed char* __restrict__ Wq,
                                                         const float* __restrict__ bias,
                                                         const unsigned* __restrict__ slots,
                                                         float* __restrict__ Y,
                                                         unsigned* __restrict__ maxY) {
  __shared__ signed char smem[65536];
  const int tid = threadIdx.x;
  const int wid = tid >> 6, lane = tid & 63;  // 4 waves
  const int wr = wid >> 1, wc = wid & 1;
  const int lr = lane & 15, lg = lane >> 4;

  // XCD-aware bijective swizzle (2048 % 8 == 0); 32 col-tiles per row-band
  const int bid = (int)blockIdx.x;
  const int swz = (bid & 7) * (NWG / 8) + (bid >> 3);
  const int brow = (swz >> 5) * 128;
  const int bcol = (swz & 31) * 128;

  // per-frag LDS row offsets / swizzle keys (row stride 128 B, 8x16B granules)
  int aoff[4], asw[4], boff[4], bsw[4];
#pragma unroll
  for (int mm = 0; mm < 4; ++mm) {
    int hr = wr * 64 + mm * 16 + lr;
    aoff[mm] = hr * 128;
    asw[mm] = hr & 7;
  }
#pragma unroll
  for (int nn = 0; nn < 4; ++nn) {
    int hr = wc * 64 + nn * 16 + lr;
    boff[nn] = hr * 128;
    bsw[nn] = hr & 7;
  }

#define ASLOT(db) (smem + (db) * 16384)
#define BSLOT(db) (smem + 32768 + (db) * 16384)
// stage one full 128x128B tile of one array: 4 x global_load_lds(16B) per wave (4 waves)
#define STAGE(gptr, grow0, kofs, slot)                                                        \
  {                                                                                           \
    _Pragma("unroll") for (int _j = 0; _j < 4; ++_j) {                                        \
      int _r = _j * 32 + wid * 8 + (lane >> 3);                                               \
      int _g = (lane & 7) ^ (_r & 7);                                                         \
      const signed char* _s = (gptr) + (size_t)((grow0) + _r) * GK + (kofs) + _g * 16;        \
      __builtin_amdgcn_global_load_lds(AS1(_s), AS3((slot) + _j * 4096 + wid * 1024), 16, 0,  \
                                       0);                                                    \
    }                                                                                         \
  }
#define LDA(mm, db, kk) \
  *(const v4i*)(ASLOT(db) + aoff[mm] + ((((kk)*4 + lg) ^ asw[mm]) << 4))
#define LDB(nn, db, kk) \
  *(const v4i*)(BSLOT(db) + boff[nn] + ((((kk)*4 + lg) ^ bsw[nn]) << 4))
#define MFMA16()                                                                              \
  __builtin_amdgcn_s_setprio(1);                                                              \
  _Pragma("unroll") for (int mm = 0; mm < 4; ++mm)                                            \
      _Pragma("unroll") for (int nn = 0; nn < 4; ++nn) acc[mm][nn] =                          \
      __builtin_amdgcn_mfma_i32_16x16x64_i8(af[mm], bf[nn], acc[mm][nn], 0, 0, 0);            \
  __builtin_amdgcn_s_setprio(0);

  // prologue: tile 0
  STAGE(Xq, brow, 0, ASLOT(0));
  STAGE(Wq, bcol, 0, BSLOT(0));

  v4i acc[4][4] = {};

#pragma unroll 2
  for (int t = 0; t < 32; ++t) {
    const int db = t & 1, ndb = db ^ 1;
    const int kof = (t + 1) * 128;
    v4i af[4], bf[4];

    // ---- gate: tile t's loads (issued during t-1, ~1 tile in flight) have landed
    asm volatile("s_waitcnt vmcnt(0)" ::: "memory");
    __builtin_amdgcn_s_barrier();
    asm volatile("" ::: "memory");

    // ---- P0: k-slice 0; stage A(t+1)
#pragma unroll
    for (int mm = 0; mm < 4; ++mm) af[mm] = LDA(mm, db, 0);
#pragma unroll
    for (int nn = 0; nn < 4; ++nn) bf[nn] = LDB(nn, db, 0);
    if (t < 31) STAGE(Xq, brow, kof, ASLOT(ndb));
    asm volatile("s_waitcnt lgkmcnt(0)");
    MFMA16()
    __builtin_amdgcn_s_barrier();
    asm volatile("" ::: "memory");

    // ---- P1: k-slice 1; stage B(t+1)
#pragma unroll
    for (int mm = 0; mm < 4; ++mm) af[mm] = LDA(mm, db, 1);
#pragma unroll
    for (int nn = 0; nn < 4; ++nn) bf[nn] = LDB(nn, db, 1);
    if (t < 31) STAGE(Wq, bcol, kof, BSLOT(ndb));
    asm volatile("s_waitcnt lgkmcnt(0)");
    MFMA16()
    __builtin_amdgcn_s_barrier();
    asm volatile("" ::: "memory");
  }

  // Epilogue: y = acc*(s_in*s_w) + round(b/s_b)*s_b ; track max|y| (block-reduced atomic)
  float s_in = fmaxf(__uint_as_float(slots[0]) / 127.0f, 1e-8f);
  float s_w = fmaxf(__uint_as_float(slots[1]) / 7.0f, 1e-8f);
  float s_b = s_in * s_w;
  float lmax = 0.0f;
#pragma unroll
  for (int n = 0; n < 4; ++n) {
    int o = bcol + wc * 64 + n * 16 + lr;
    float bdq = rintf(bias[o] / s_b) * s_b;
#pragma unroll
    for (int m = 0; m < 4; ++m) {
      int t0 = brow + wr * 64 + m * 16 + (lg << 2);
#pragma unroll
      for (int r2 = 0; r2 < 4; ++r2) {
        float yv = (float)acc[m][n][r2] * s_b + bdq;
        Y[(size_t)(t0 + r2) * GN + o] = yv;
        lmax = fmaxf(lmax, fabsf(yv));
      }
    }
  }
  for (int off = 32; off; off >>= 1) lmax = fmaxf(lmax, __shfl_xor(lmax, off));
  float* fred = (float*)smem;  // K-loop fully barriered -> safe reuse
  __syncthreads();
  if (lane == 0) fred[wid] = lmax;
  __syncthreads();
  if (tid == 0) {
    float m = fmaxf(fmaxf(fred[0], fred[1]), fmaxf(fred[2], fred[3]));
    atomicMax(maxY, __float_as_uint(m));
  }
#undef STAGE
#undef ASLOT
#undef BSLOT
#undef LDA
#undef LDB
#undef MFMA16
}

// ---------------- output quant in-place on d_out --------------------------------------------
__global__ __launch_bounds__(256) void quant_out_kernel(float* __restrict__ y, int n4,
                                                        const unsigned* __restrict__ slot) {
  float s = fmaxf(__uint_as_float(*slot) / 127.0f, 1e-8f);
  float inv = 1.0f / s;
  int tid = blockIdx.x * blockDim.x + threadIdx.x;
  int stride = gridDim.x * blockDim.x;
  float4* y4 = (float4*)y;
  for (int i = tid; i < n4; i += stride) {
    float4 v = y4[i];
    v.x = fminf(fmaxf(rintf(v.x * inv), -128.0f), 127.0f) * s;
    v.y = fminf(fmaxf(rintf(v.y * inv), -128.0f), 127.0f) * s;
    v.z = fminf(fmaxf(rintf(v.z * inv), -128.0f), 127.0f) * s;
    v.w = fminf(fmaxf(rintf(v.w * inv), -128.0f), 127.0f) * s;
    y4[i] = v;
  }
}

extern "C" void kernel_launch(void* const* d_in, const int* in_sizes, int n_in,
                              void* d_out, int out_size, void* d_ws, size_t ws_size,
                              hipStream_t stream) {
  const float* inp = (const float*)d_in[0];  // [8192,4096]
  const float* W = (const float*)d_in[1];    // [4096,4096]
  const float* b = (const float*)d_in[2];    // [4096]
  float* out = (float*)d_out;                // [8192,4096]

  unsigned* slots = (unsigned*)d_ws;  // [0]=max|X|, [1]=max|W|, [2]=max|Y| (float bits)
  signed char* Xq = (signed char*)d_ws + 256;
  signed char* Wq = Xq + (size_t)GM * GK;

  const int nX = GM * GK;
  const int nW = GN * GK;

  // zero the atomic-max slots (ws is NOT re-poisoned between timed replays)
  hipMemsetAsync(d_ws, 0, 16, stream);

  maxabs_kernel<<<1024, 256, 0, stream>>>(inp, nX / 4, slots + 0);
  maxabs_kernel<<<512, 256, 0, stream>>>(W, nW / 4, slots + 1);

  quant_kernel<<<1024, 256, 0, stream>>>(inp, Xq, nX / 4, slots + 0, 127.0f, -128.0f, 127.0f);
  quant_kernel<<<512, 256, 0, stream>>>(W, Wq, nW / 4, slots + 1, 7.0f, -8.0f, 7.0f);

  gemm_i8_kernel<<<NWG, 256, 0, stream>>>(Xq, Wq, b, slots, out, slots + 2);

  quant_out_kernel<<<1024, 256, 0, stream>>>(out, (GM * GN) / 4, slots + 2);
}